// Round 3
// baseline (1441.431 us; speedup 1.0000x reference)
//
#include <hip/hip_runtime.h>
#include <hip/hip_bf16.h>
#include <math.h>

// B=64 T=64 D=8 F=1024 H=1024 C=22 IN=4096; N rows = B*T = 4096.
// Dtype-adaptive: a detector kernel decides whether d_in is fp32 (reference
// dtype) or bf16 (harness-converted); converters canonicalize everything into
// bf16 ws buffers (weights pre-permuted for the LSTM gate interleave), biases
// into fp32; GEMMs are pure-bf16 m97-style; epilogue stores d_out per flag.
//
// ws layout (138 MB):
//   0    cbuf   fp32 [4096][1024]                16 MB
//   16M  AH0    bf16 [4096][2048] ping ([in|h])  16 MB
//   32M  AH1    bf16 [4096][2048] pong           16 MB
//   48M  feats  bf16 [4096][1024]                 8 MB
//   56M  wsX    bf16 [4096][4096]                32 MB
//   88M  wsWf   bf16 [1024][4096]                 8 MB
//   96M  wsDecW bf16 [4096][2048] (permuted)     16 MB
//   112M wsEncW bf16 [4096][2048] (permuted)     16 MB
//   128M wsWdc  bf16 [1024][1024]                 2 MB
//   130M wsWec  bf16 [22][1024]                   1 MB reserved
//   131M wsBias fp32 [18454]  (bf|dbih|dbhh|bdc|ebih|ebhh|bec)
//   131M+128K flag int

typedef __attribute__((ext_vector_type(8))) short short8;
typedef __attribute__((ext_vector_type(4))) float f32x4;

#define BM 128
#define BN 128
#define BK 64

__device__ __forceinline__ float sigm(float x) { return 1.0f / (1.0f + __expf(-x)); }
__device__ __forceinline__ unsigned short f2bf(float f) {
  unsigned u = __float_as_uint(f);
  u += 0x7FFFu + ((u >> 16) & 1u);       // RNE
  return (unsigned short)(u >> 16);
}
__device__ __forceinline__ float bf2f(unsigned short h) {
  return __uint_as_float(((unsigned)h) << 16);
}

__global__ void zero_kernel(uint4* p, int n) {
  int i = blockIdx.x * blockDim.x + threadIdx.x;
  int st = gridDim.x * blockDim.x;
  uint4 z = make_uint4(0u, 0u, 0u, 0u);
  for (; i < n; i += st) p[i] = z;
}

// Decide fp32 vs bf16 by scanning x's 16-bit halves: fp32 data has mantissa
// halves whose bf16-exponent field is huge/NaN-range (>=0xC0, i.e. |v|>=2^65)
// with ~25% probability; real bf16 N(0,1) data never does.
__global__ void detect_kernel(const unsigned short* x, int* flag) {
  __shared__ int s;
  if (threadIdx.x == 0) s = 0;
  __syncthreads();
  int bad = 0;
  for (int i = threadIdx.x; i < 8192; i += 256) {
    unsigned e = (x[i] >> 7) & 0xFFu;
    if (e >= 0xC0u) bad = 1;
  }
  if (bad) atomicOr(&s, 1);
  __syncthreads();
  if (threadIdx.x == 0) *flag = s;   // 1 = fp32 inputs
}

__global__ void cvt_plain(const void* __restrict__ src, unsigned short* __restrict__ dst,
                          int n4, const int* __restrict__ flag) {
  int f = *flag;
  int i = blockIdx.x * blockDim.x + threadIdx.x;
  int st = gridDim.x * blockDim.x;
  if (f) {
    const float4* s = (const float4*)src;
    for (; i < n4; i += st) {
      float4 v = s[i];
      ushort4 o; o.x = f2bf(v.x); o.y = f2bf(v.y); o.z = f2bf(v.z); o.w = f2bf(v.w);
      ((ushort4*)dst)[i] = o;
    }
  } else {
    const ushort4* s = (const ushort4*)src;
    for (; i < n4; i += st) ((ushort4*)dst)[i] = s[i];
  }
}

// dst[p][k], p in [0,4096), k in [0,2048): the gate-interleaved concat
// [Wih | Whh]: packed col p -> orig gate row gate*1024+unit with gate=(p>>4)&3,
// unit=((p>>6)<<4)|(p&15); so a wave's 4 n-frags hold i,f,g,o of one unit.
__global__ void cvt_lstmw(const void* __restrict__ Wih, const void* __restrict__ Whh,
                          unsigned short* __restrict__ dst, const int* __restrict__ flag) {
  int f = *flag;
  int idx = blockIdx.x * blockDim.x + threadIdx.x;   // over 4096*512 vec4 groups
  if (idx >= 4096 * 512) return;
  int p = idx >> 9;
  int k = (idx & 511) * 4;
  int gate = (p >> 4) & 3, unit = ((p >> 6) << 4) | (p & 15);
  size_t orig = (size_t)(gate * 1024 + unit);
  const void* sm; int kk;
  if (k < 1024) { sm = Wih; kk = k; } else { sm = Whh; kk = k - 1024; }
  size_t off = orig * 1024 + kk;
  ushort4 o;
  if (f) {
    float4 v = *(const float4*)((const float*)sm + off);
    o.x = f2bf(v.x); o.y = f2bf(v.y); o.z = f2bf(v.z); o.w = f2bf(v.w);
  } else {
    o = *(const ushort4*)((const unsigned short*)sm + off);
  }
  ((ushort4*)dst)[idx] = o;
}

// concat 7 bias vectors to fp32: offsets bf=0 dbih=1024 dbhh=5120 bdc=9216
// ebih=10240 ebhh=14336 bec=18432 (total 18454)
__global__ void cvt_bias(const void* s0, const void* s1, const void* s2, const void* s3,
                         const void* s4, const void* s5, const void* s6,
                         float* __restrict__ dst, const int* __restrict__ flag) {
  int f = *flag;
  int i = blockIdx.x * blockDim.x + threadIdx.x;
  if (i >= 18454) return;
  const void* s; int j;
  if      (i < 1024)  { s = s0; j = i; }
  else if (i < 5120)  { s = s1; j = i - 1024; }
  else if (i < 9216)  { s = s2; j = i - 5120; }
  else if (i < 10240) { s = s3; j = i - 9216; }
  else if (i < 14336) { s = s4; j = i - 10240; }
  else if (i < 18432) { s = s5; j = i - 14336; }
  else                { s = s6; j = i - 18432; }
  dst[i] = f ? ((const float*)s)[j] : bf2f(((const unsigned short*)s)[j]);
}

// NT GEMM, all operands bf16 (ws-canonical). A split at BK-aligned splitKA
// (A0/ldA0 then A1/ldA1) for the encoder's [feats | enc_h0]. B[nB][K], row
// clamped to nB-1 (no skipped loads -> no uninit LDS); cols >= ncol masked.
// mode 1: v = (relu?)(acc + bias0[col]); store to d_out at foff+row*ldf+col
//   (fp32 or bf16 per *of32), plus bf16 dual-stores pb1 (*sb1) and pb2.
// mode 2: LSTM cell; n-frags = i,f,g,o of unit u; c fp32 in-place; h -> hptr.
__global__ __launch_bounds__(256, 2) void gemm_fused(
    const unsigned short* __restrict__ A0, int ldA0,
    const unsigned short* __restrict__ A1, int ldA1, int splitKA,
    const unsigned short* __restrict__ B, int K, int nB,
    const float* __restrict__ bias0, const float* __restrict__ bias1,
    int mode, int do_relu,
    void* __restrict__ pf, long long foff, long long ldf, int ncol,
    const int* __restrict__ of32flag,
    unsigned short* __restrict__ pb1, long long ldb1, float sb1,
    unsigned short* __restrict__ pb2, long long ldb2,
    float* __restrict__ cbuf, unsigned short* __restrict__ hptr, long long h_ldc)
{
  __shared__ unsigned short As[BM * BK];
  __shared__ unsigned short Bs[BN * BK];

  const int tid  = threadIdx.x;
  const int wv   = tid >> 6;
  const int lane = tid & 63;
  const int l15  = lane & 15;
  const int quad = lane >> 4;
  const int wm   = wv & 1;
  const int wn   = wv >> 1;
  const int row0 = blockIdx.y * BM;
  const int col0 = blockIdx.x * BN;

  f32x4 acc[4][4];
#pragma unroll
  for (int i = 0; i < 4; ++i)
#pragma unroll
    for (int j = 0; j < 4; ++j) acc[i][j] = (f32x4){0.f, 0.f, 0.f, 0.f};

  for (int k0 = 0; k0 < K; k0 += BK) {
    __syncthreads();
    const unsigned short* Ab; int kA, ldA;
    if (k0 < splitKA) { Ab = A0; kA = k0;           ldA = ldA0; }
    else              { Ab = A1; kA = k0 - splitKA; ldA = ldA1; }

#pragma unroll
    for (int it = 0; it < 4; ++it) {
      int e = (it * 256 + tid) * 8;
      int r = e >> 6, c = e & 63;
      const unsigned short* src = Ab + (size_t)(row0 + r) * ldA + (kA + c);
      unsigned short* dst = As + (size_t)(it * 256 + wv * 64) * 8;  // wave-uniform base
      __builtin_amdgcn_global_load_lds((const __attribute__((address_space(1))) void*)src,
                                       (__attribute__((address_space(3))) void*)dst, 16, 0, 0);
    }
#pragma unroll
    for (int it = 0; it < 4; ++it) {
      int e = (it * 256 + tid) * 8;
      int r = e >> 6, c = e & 63;
      int p = col0 + r;
      int pr = (p < nB) ? p : (nB - 1);   // clamp, never skip
      const unsigned short* src = B + (size_t)pr * K + (k0 + c);
      unsigned short* dst = Bs + (size_t)(it * 256 + wv * 64) * 8;
      __builtin_amdgcn_global_load_lds((const __attribute__((address_space(1))) void*)src,
                                       (__attribute__((address_space(3))) void*)dst, 16, 0, 0);
    }
    __syncthreads();
#pragma unroll
    for (int kk = 0; kk < BK; kk += 32) {
      short8 av[4], bv[4];
#pragma unroll
      for (int i = 0; i < 4; ++i)
        av[i] = *reinterpret_cast<const short8*>(&As[(wm * 64 + i * 16 + l15) * BK + kk + quad * 8]);
#pragma unroll
      for (int j = 0; j < 4; ++j)
        bv[j] = *reinterpret_cast<const short8*>(&Bs[(wn * 64 + j * 16 + l15) * BK + kk + quad * 8]);
#pragma unroll
      for (int i = 0; i < 4; ++i)
#pragma unroll
        for (int j = 0; j < 4; ++j)
          acc[i][j] = __builtin_amdgcn_mfma_f32_16x16x32_bf16(av[i], bv[j], acc[i][j], 0, 0, 0);
    }
  }

  // C/D layout (m89-verified): col = lane&15, row = quad*4 + reg
  const int rb = row0 + wm * 64 + quad * 4;
  const int cb = col0 + wn * 64;

  if (mode == 1) {
    const int of32 = pf ? *of32flag : 1;  // uniform scalar load
#pragma unroll
    for (int mi = 0; mi < 4; ++mi) {
#pragma unroll
      for (int r = 0; r < 4; ++r) {
        long long row = rb + mi * 16 + r;
#pragma unroll
        for (int nj = 0; nj < 4; ++nj) {
          int col = cb + nj * 16 + l15;
          if (col < ncol) {
            float v = acc[mi][nj][r] + bias0[col];
            if (do_relu) v = fmaxf(v, 0.f);
            if (pf) {
              long long oi = foff + row * ldf + col;
              if (of32) ((float*)pf)[oi] = v;
              else      ((unsigned short*)pf)[oi] = f2bf(v);
            }
            if (pb1) pb1[row * ldb1 + col] = f2bf(v * sb1);
            if (pb2) pb2[row * ldb2 + col] = f2bf(v);
          }
        }
      }
    }
  } else {
    const int u = ((cb >> 6) << 4) | l15;
    const float bi = bias0[u]        + bias1[u];
    const float bff= bias0[1024 + u] + bias1[1024 + u];
    const float bg = bias0[2048 + u] + bias1[2048 + u];
    const float bo = bias0[3072 + u] + bias1[3072 + u];
#pragma unroll
    for (int mi = 0; mi < 4; ++mi) {
#pragma unroll
      for (int r = 0; r < 4; ++r) {
        long long row = rb + mi * 16 + r;
        float iv = acc[mi][0][r] + bi;
        float fv = acc[mi][1][r] + bff;
        float gv = acc[mi][2][r] + bg;
        float ov = acc[mi][3][r] + bo;
        float co = cbuf[row * 1024 + u];
        float cn = sigm(fv) * co + sigm(iv) * tanhf(gv);
        cbuf[row * 1024 + u] = cn;
        hptr[row * h_ldc + u] = f2bf(sigm(ov) * tanhf(cn));
      }
    }
  }
}

extern "C" void kernel_launch(void* const* d_in, const int* in_sizes, int n_in,
                              void* d_out, int out_size, void* d_ws, size_t ws_size,
                              hipStream_t stream) {
  const void* x    = d_in[0];
  const void* Wf   = d_in[1];
  const void* bf_  = d_in[2];
  const void* dWih = d_in[3];
  const void* dWhh = d_in[4];
  const void* dbih = d_in[5];
  const void* dbhh = d_in[6];
  const void* Wdc  = d_in[7];
  const void* bdc  = d_in[8];
  const void* eWih = d_in[9];
  const void* eWhh = d_in[10];
  const void* ebih = d_in[11];
  const void* ebhh = d_in[12];
  const void* Wec  = d_in[13];
  const void* bec  = d_in[14];

  char* w = (char*)d_ws;
  const size_t MB = 1u << 20;
  float*          cbuf  = (float*)(w);
  unsigned short* AH0   = (unsigned short*)(w + 16 * MB);
  unsigned short* AH1   = (unsigned short*)(w + 32 * MB);
  unsigned short* feats = (unsigned short*)(w + 48 * MB);
  unsigned short* wsX   = (unsigned short*)(w + 56 * MB);
  unsigned short* wsWf  = (unsigned short*)(w + 88 * MB);
  unsigned short* wsDecW= (unsigned short*)(w + 96 * MB);
  unsigned short* wsEncW= (unsigned short*)(w + 112 * MB);
  unsigned short* wsWdc = (unsigned short*)(w + 128 * MB);
  unsigned short* wsWec = (unsigned short*)(w + 130 * MB);
  float*          wsB   = (float*)(w + 131 * MB);
  int*            flag  = (int*)(w + 131 * MB + 128 * 1024);

  const int BIG = 1 << 30;

  // 1) dtype detect
  detect_kernel<<<1, 256, 0, stream>>>((const unsigned short*)x, flag);
  // 2) zero cbuf (c0) + AH0 (h0; left half overwritten by L1)
  zero_kernel<<<2048, 256, 0, stream>>>((uint4*)w, (32u << 20) / 16);
  // 3) canonicalize inputs to bf16 ws (or copy if already bf16)
  cvt_plain<<<4096, 256, 0, stream>>>(x,   wsX,  16777216 / 4, flag);
  cvt_plain<<<2048, 256, 0, stream>>>(Wf,  wsWf,  4194304 / 4, flag);
  cvt_plain<<<1024, 256, 0, stream>>>(Wdc, wsWdc, 1048576 / 4, flag);
  cvt_plain<<<22,   256, 0, stream>>>(Wec, wsWec,   22528 / 4, flag);
  cvt_lstmw<<<8192, 256, 0, stream>>>(dWih, dWhh, wsDecW, flag);
  cvt_lstmw<<<8192, 256, 0, stream>>>(eWih, eWhh, wsEncW, flag);
  cvt_bias<<<73, 256, 0, stream>>>(bf_, dbih, dbhh, bdc, ebih, ebhh, bec, wsB, flag);

  // out element offsets (dtype-agnostic): enc at 0 ([4096][22]), dec at 90112
  // (idx = 90112 + d*1024 + row*8192 + col)

  // 4) L1: feats = relu(x @ Wf^T + bf) -> AH0 left + feats
  gemm_fused<<<dim3(8, 32), 256, 0, stream>>>(
      wsX, 4096, nullptr, 0, BIG, wsWf, 4096, 1024, wsB, nullptr,
      1, 1, nullptr, 0, 0, BIG, flag, AH0, 2048, 1.0f, feats, 1024, nullptr, nullptr, 0);

  // 5) decoder: 8 recurrence steps
  for (int d = 0; d < 8; ++d) {
    unsigned short* cur = (d & 1) ? AH1 : AH0;
    unsigned short* nxt = (d & 1) ? AH0 : AH1;
    gemm_fused<<<dim3(32, 32), 256, 0, stream>>>(
        cur, 2048, nullptr, 0, BIG, wsDecW, 2048, 4096, wsB + 1024, wsB + 5120,
        2, 0, nullptr, 0, 0, BIG, flag, nullptr, 0, 0.f, nullptr, 0,
        cbuf, nxt + 1024, 2048);
    unsigned short* pb1 = (d < 7) ? nxt : AH1;     // next input, or enc_h0=out/8
    float sb1 = (d < 7) ? 1.0f : 0.125f;
    gemm_fused<<<dim3(8, 32), 256, 0, stream>>>(
        nxt + 1024, 2048, nullptr, 0, BIG, wsWdc, 1024, 1024, wsB + 9216, nullptr,
        1, 0, d_out, 90112 + (long long)d * 1024, 8192, BIG, flag,
        pb1, 2048, sb1, nullptr, 0, nullptr, nullptr, 0);
  }

  // 6) encoder: re-zero c; one step on A = [feats | enc_h0(AH1 left)]
  zero_kernel<<<1024, 256, 0, stream>>>((uint4*)cbuf, (16u << 20) / 16);
  gemm_fused<<<dim3(32, 32), 256, 0, stream>>>(
      feats, 1024, AH1, 2048, 1024, wsEncW, 2048, 4096, wsB + 10240, wsB + 14336,
      2, 0, nullptr, 0, 0, BIG, flag, nullptr, 0, 0.f, nullptr, 0,
      cbuf, AH0, 2048);

  // 7) classifier: enc_scores = ench(AH0 left) @ Wec^T + bec
  gemm_fused<<<dim3(1, 32), 256, 0, stream>>>(
      AH0, 2048, nullptr, 0, BIG, wsWec, 1024, 22, wsB + 18432, nullptr,
      1, 0, d_out, 0, 22, 22, flag, nullptr, 0, 0.f, nullptr, 0,
      nullptr, nullptr, 0);
}

// Round 4
// 929.982 us; speedup vs baseline: 1.5500x; 1.5500x over previous
//
#include <hip/hip_runtime.h>
#include <hip/hip_bf16.h>
#include <math.h>

// B=64 T=64 D=8 F=1024 H=1024 C=22 IN=4096; N rows = B*T = 4096.
// Decoder recurrence algebraically fused: for d>=1,
//   gates(d) = h(d-1) @ (Wih@Wdc + Whh)^T + (Wih@bdc + bih + bhh)   [K=1024]
// dec_scores batched into ONE M=32768 GEMM at the end.
//
// ws layout (MB):
//  0   cbuf   fp32 [4096][1024]            16
//  16  wsH    bf16 [8][4096][1024]         64   (wsX overlays 16..48; ench overlays wsH[0])
//  80  feats  bf16 [4096][1024]             8
//  88  encH0  bf16 [4096][1024]             8
//  96  wsDecW bf16 [4096][2048] permuted   16
//  112 wsEncW bf16 [4096][2048] permuted   16
//  128 wsWf   bf16 [1024][4096]             8
//  136 wsWdc  bf16 [1024][1024]             2
//  138 wsWdcT bf16 [1024][1024] (Wdc^T)     2
//  140 wsWfus bf16 [4096][1024] permuted    8
//  148 wsWec  bf16 [22][1024]
//  149 wsB    fp32 [10262]  bf|decsum|encsum|bdc|bec
//  149+64K  wsBfus fp32 [4096]
//  149+96K  flag

typedef __attribute__((ext_vector_type(8))) short short8;
typedef __attribute__((ext_vector_type(4))) float f32x4;

#define BM 128
#define BN 128
#define BK 64

#define EPI_LIN    1
#define EPI_LSTM   2
#define EPI_SCORES 4
#define EPI_CLS    5

__device__ __forceinline__ float sigm(float x) { return 1.0f / (1.0f + __expf(-x)); }
__device__ __forceinline__ float tanh_f(float x) { return 1.0f - 2.0f / (__expf(2.0f * x) + 1.0f); }
__device__ __forceinline__ unsigned short f2bf(float f) {
  unsigned u = __float_as_uint(f);
  u += 0x7FFFu + ((u >> 16) & 1u);       // RNE
  return (unsigned short)(u >> 16);
}
__device__ __forceinline__ float bf2f(unsigned short h) {
  return __uint_as_float(((unsigned)h) << 16);
}

// fp32-vs-bf16 input detection: fp32 mantissa halves hit huge bf16 exponents.
__global__ void detect_kernel(const unsigned short* x, int* flag) {
  __shared__ int s;
  if (threadIdx.x == 0) s = 0;
  __syncthreads();
  int bad = 0;
  for (int i = threadIdx.x; i < 8192; i += 256) {
    unsigned e = (x[i] >> 7) & 0xFFu;
    if (e >= 0xC0u) bad = 1;
  }
  if (bad) atomicOr(&s, 1);
  __syncthreads();
  if (threadIdx.x == 0) *flag = s;   // 1 = fp32 inputs
}

__global__ void cvt_plain(const void* __restrict__ src, unsigned short* __restrict__ dst,
                          int n4, const int* __restrict__ flag) {
  int f = *flag;
  int i = blockIdx.x * blockDim.x + threadIdx.x;
  int st = gridDim.x * blockDim.x;
  if (f) {
    const float4* s = (const float4*)src;
    for (; i < n4; i += st) {
      float4 v = s[i];
      ushort4 o; o.x = f2bf(v.x); o.y = f2bf(v.y); o.z = f2bf(v.z); o.w = f2bf(v.w);
      ((ushort4*)dst)[i] = o;
    }
  } else {
    const ushort4* s = (const ushort4*)src;
    for (; i < n4; i += st) ((ushort4*)dst)[i] = s[i];
  }
}

// Gate-interleaved permuted concat [Wih | Whh] -> dst[4096][2048].
// packed row p -> orig gate row gate*1024+unit, gate=(p>>4)&3, unit=((p>>6)<<4)|(p&15)
__global__ void cvt_lstmw(const void* __restrict__ Wih, const void* __restrict__ Whh,
                          unsigned short* __restrict__ dst, const int* __restrict__ flag) {
  int f = *flag;
  int idx = blockIdx.x * blockDim.x + threadIdx.x;   // 4096*512 vec4 groups
  if (idx >= 4096 * 512) return;
  int p = idx >> 9;
  int k = (idx & 511) * 4;
  int gate = (p >> 4) & 3, unit = ((p >> 6) << 4) | (p & 15);
  size_t orig = (size_t)(gate * 1024 + unit);
  const void* sm; int kk;
  if (k < 1024) { sm = Wih; kk = k; } else { sm = Whh; kk = k - 1024; }
  size_t off = orig * 1024 + kk;
  ushort4 o;
  if (f) {
    float4 v = *(const float4*)((const float*)sm + off);
    o.x = f2bf(v.x); o.y = f2bf(v.y); o.z = f2bf(v.z); o.w = f2bf(v.w);
  } else {
    o = *(const ushort4*)((const unsigned short*)sm + off);
  }
  ((ushort4*)dst)[idx] = o;
}

// wsB: [0,1024)=bf  [1024,5120)=dbih+dbhh  [5120,9216)=ebih+ebhh
//      [9216,10240)=bdc  [10240,10262)=bec
__global__ void cvt_bias(const void* s0, const void* s1, const void* s2, const void* s3,
                         const void* s4, const void* s5, const void* s6,
                         float* __restrict__ dst, const int* __restrict__ flag) {
  int f = *flag;
  int i = blockIdx.x * blockDim.x + threadIdx.x;
  if (i >= 10262) return;
  auto ld = [f](const void* s, int j) -> float {
    return f ? ((const float*)s)[j] : bf2f(((const unsigned short*)s)[j]);
  };
  float v;
  if      (i < 1024)  v = ld(s0, i);
  else if (i < 5120)  v = ld(s1, i - 1024) + ld(s2, i - 1024);
  else if (i < 9216)  v = ld(s3, i - 5120) + ld(s4, i - 5120);
  else if (i < 10240) v = ld(s5, i - 9216);
  else                v = ld(s6, i - 10240);
  dst[i] = v;
}

// wsWdcT[n][k] = Wdc[k][n]  (bf16 out, dtype-adaptive in)
__global__ void trans_wdc(const void* __restrict__ src, unsigned short* __restrict__ dst,
                          const int* __restrict__ flag) {
  __shared__ float t[32][33];
  int f = *flag;
  int bx = blockIdx.x, by = blockIdx.y;
  int tx = threadIdx.x & 31, ty = threadIdx.x >> 5;
  for (int r = ty; r < 32; r += 8) {
    int sr = by * 32 + r, sc = bx * 32 + tx;
    t[r][tx] = f ? ((const float*)src)[(size_t)sr * 1024 + sc]
                 : bf2f(((const unsigned short*)src)[(size_t)sr * 1024 + sc]);
  }
  __syncthreads();
  for (int r = ty; r < 32; r += 8)
    dst[(size_t)(bx * 32 + r) * 1024 + by * 32 + tx] = f2bf(t[tx][r]);
}

// wsBfus[i] = decsum[i] + sum_j Wih[i][j]*bdc[j]   (orig gate-row index i)
__global__ void bias_dot(const void* __restrict__ Wih, const float* __restrict__ wsB,
                         float* __restrict__ out, const int* __restrict__ flag) {
  int i = blockIdx.x;
  int f = *flag;
  const float* bdc = wsB + 9216;
  float s = 0.f;
  for (int j = threadIdx.x; j < 1024; j += 256) {
    float wv = f ? ((const float*)Wih)[(size_t)i * 1024 + j]
                 : bf2f(((const unsigned short*)Wih)[(size_t)i * 1024 + j]);
    s += wv * bdc[j];
  }
  __shared__ float red[4];
  for (int o = 32; o > 0; o >>= 1) s += __shfl_down(s, o, 64);
  if ((threadIdx.x & 63) == 0) red[threadIdx.x >> 6] = s;
  __syncthreads();
  if (threadIdx.x == 0) out[i] = wsB[1024 + i] + red[0] + red[1] + red[2] + red[3];
}

// NT GEMM C = A@B^T (bf16 in, fp32 acc), 128x128 tile, BK=64, LDS chunk-XOR
// swizzle (c8 ^= r&7 at stage time, compensated in ds_read) to kill the
// 16-way 128B-stride bank conflicts. A split at BK-aligned splitKA.
// B rows clamped to nB-1 (no skipped DMA -> no uninit LDS).
__global__ __launch_bounds__(256, 2) void gemm_fused(
    const unsigned short* __restrict__ A0, int ldA0,
    const unsigned short* __restrict__ A1, int ldA1, int splitKA,
    const unsigned short* __restrict__ B, int ldB, int K, int nB,
    const float* __restrict__ bias0,
    int mode, int do_relu, int czero,
    unsigned short* __restrict__ p1, long long ldc1,
    const unsigned short* __restrict__ addm, long long ldadd,
    void* __restrict__ dov, const int* __restrict__ of32flag,
    unsigned short* __restrict__ encH0,
    float* __restrict__ cbuf, int ncol)
{
  __shared__ unsigned short As[BM * BK];
  __shared__ unsigned short Bs[BN * BK];

  const int tid  = threadIdx.x;
  const int wv   = tid >> 6;
  const int lane = tid & 63;
  const int l15  = lane & 15;
  const int l7   = lane & 7;
  const int quad = lane >> 4;
  const int wm   = wv & 1;
  const int wn   = wv >> 1;
  const int row0 = blockIdx.y * BM;
  const int col0 = blockIdx.x * BN;

  f32x4 acc[4][4];
#pragma unroll
  for (int i = 0; i < 4; ++i)
#pragma unroll
    for (int j = 0; j < 4; ++j) acc[i][j] = (f32x4){0.f, 0.f, 0.f, 0.f};

  for (int k0 = 0; k0 < K; k0 += BK) {
    __syncthreads();
    const unsigned short* Ab; int kA, ldA;
    if (k0 < splitKA) { Ab = A0; kA = k0;           ldA = ldA0; }
    else              { Ab = A1; kA = k0 - splitKA; ldA = ldA1; }

#pragma unroll
    for (int it = 0; it < 4; ++it) {
      int e  = (it * 256 + tid) * 8;
      int r  = e >> 6;
      int c8 = (e >> 3) & 7;
      int sc = ((c8 ^ (r & 7)) << 3);            // chunk-XOR swizzle
      const unsigned short* src = Ab + (size_t)(row0 + r) * ldA + (kA + sc);
      unsigned short* dst = As + (size_t)(it * 256 + wv * 64) * 8;
      __builtin_amdgcn_global_load_lds((const __attribute__((address_space(1))) void*)src,
                                       (__attribute__((address_space(3))) void*)dst, 16, 0, 0);
    }
#pragma unroll
    for (int it = 0; it < 4; ++it) {
      int e  = (it * 256 + tid) * 8;
      int r  = e >> 6;
      int c8 = (e >> 3) & 7;
      int sc = ((c8 ^ (r & 7)) << 3);
      int p  = col0 + r;
      int pr = (p < nB) ? p : (nB - 1);
      const unsigned short* src = B + (size_t)pr * ldB + (k0 + sc);
      unsigned short* dst = Bs + (size_t)(it * 256 + wv * 64) * 8;
      __builtin_amdgcn_global_load_lds((const __attribute__((address_space(1))) void*)src,
                                       (__attribute__((address_space(3))) void*)dst, 16, 0, 0);
    }
    __syncthreads();
#pragma unroll
    for (int kk = 0; kk < BK; kk += 32) {
      const int ko = kk >> 3;                    // 0 or 4
      short8 av[4], bv[4];
#pragma unroll
      for (int i = 0; i < 4; ++i) {
        int R = wm * 64 + i * 16 + l15;
        av[i] = *reinterpret_cast<const short8*>(&As[R * BK + (((quad + ko) ^ l7 & 7) << 3)]);
      }
#pragma unroll
      for (int j = 0; j < 4; ++j) {
        int R = wn * 64 + j * 16 + l15;
        bv[j] = *reinterpret_cast<const short8*>(&Bs[R * BK + (((quad + ko) ^ l7 & 7) << 3)]);
      }
#pragma unroll
      for (int i = 0; i < 4; ++i)
#pragma unroll
        for (int j = 0; j < 4; ++j)
          acc[i][j] = __builtin_amdgcn_mfma_f32_16x16x32_bf16(av[i], bv[j], acc[i][j], 0, 0, 0);
    }
  }

  // C/D layout (m89): col = lane&15, row = quad*4 + reg
  const int rb = row0 + wm * 64 + quad * 4;
  const int cb = col0 + wn * 64;

  if (mode == EPI_LIN) {
#pragma unroll
    for (int mi = 0; mi < 4; ++mi)
#pragma unroll
      for (int r = 0; r < 4; ++r) {
        long long row = rb + mi * 16 + r;
#pragma unroll
        for (int nj = 0; nj < 4; ++nj) {
          int col = cb + nj * 16 + l15;
          float v = acc[mi][nj][r] + (bias0 ? bias0[col] : 0.f);
          if (addm) v += bf2f(addm[row * ldadd + col]);
          if (do_relu) v = fmaxf(v, 0.f);
          p1[row * ldc1 + col] = f2bf(v);
        }
      }
  } else if (mode == EPI_LSTM) {
    const int u = ((cb >> 6) << 4) | l15;
    const float bi = bias0[u];
    const float bff= bias0[1024 + u];
    const float bg = bias0[2048 + u];
    const float bo = bias0[3072 + u];
#pragma unroll
    for (int mi = 0; mi < 4; ++mi)
#pragma unroll
      for (int r = 0; r < 4; ++r) {
        long long row = rb + mi * 16 + r;
        float iv = acc[mi][0][r] + bi;
        float fv = acc[mi][1][r] + bff;
        float gv = acc[mi][2][r] + bg;
        float ov = acc[mi][3][r] + bo;
        float co = czero ? 0.f : cbuf[row * 1024 + u];
        float cn = sigm(fv) * co + sigm(iv) * tanh_f(gv);
        cbuf[row * 1024 + u] = cn;
        p1[row * ldc1 + u] = f2bf(sigm(ov) * tanh_f(cn));
      }
  } else if (mode == EPI_SCORES) {
    const int of32 = *of32flag;
#pragma unroll
    for (int mi = 0; mi < 4; ++mi)
#pragma unroll
      for (int r = 0; r < 4; ++r) {
        long long row = rb + mi * 16 + r;
        long long d = row >> 12, n = row & 4095;
#pragma unroll
        for (int nj = 0; nj < 4; ++nj) {
          int col = cb + nj * 16 + l15;
          float v = acc[mi][nj][r] + bias0[col];
          long long oi = 90112 + d * 1024 + n * 8192 + col;
          if (of32) ((float*)dov)[oi] = v;
          else      ((unsigned short*)dov)[oi] = f2bf(v);
          if (row >= 28672) encH0[n * 1024 + col] = f2bf(v * 0.125f);
        }
      }
  } else {  // EPI_CLS
    const int of32 = *of32flag;
#pragma unroll
    for (int mi = 0; mi < 4; ++mi)
#pragma unroll
      for (int r = 0; r < 4; ++r) {
        long long row = rb + mi * 16 + r;
#pragma unroll
        for (int nj = 0; nj < 4; ++nj) {
          int col = cb + nj * 16 + l15;
          if (col < ncol) {
            float v = acc[mi][nj][r] + bias0[col];
            long long oi = row * ncol + col;
            if (of32) ((float*)dov)[oi] = v;
            else      ((unsigned short*)dov)[oi] = f2bf(v);
          }
        }
      }
  }
}

extern "C" void kernel_launch(void* const* d_in, const int* in_sizes, int n_in,
                              void* d_out, int out_size, void* d_ws, size_t ws_size,
                              hipStream_t stream) {
  const void* x    = d_in[0];
  const void* Wf   = d_in[1];
  const void* bf_  = d_in[2];
  const void* dWih = d_in[3];
  const void* dWhh = d_in[4];
  const void* dbih = d_in[5];
  const void* dbhh = d_in[6];
  const void* Wdc  = d_in[7];
  const void* bdc  = d_in[8];
  const void* eWih = d_in[9];
  const void* eWhh = d_in[10];
  const void* ebih = d_in[11];
  const void* ebhh = d_in[12];
  const void* Wec  = d_in[13];
  const void* bec  = d_in[14];

  char* w = (char*)d_ws;
  const size_t MB = 1u << 20;
  float*          cbuf   = (float*)(w);
  unsigned short* wsH    = (unsigned short*)(w + 16 * MB);   // [8][4096][1024]
  unsigned short* wsX    = (unsigned short*)(w + 16 * MB);   // overlays wsH[0..3] (dead after L1)
  unsigned short* ench   = (unsigned short*)(w + 16 * MB);   // overlays wsH[0] (after scores GEMM)
  unsigned short* feats  = (unsigned short*)(w + 80 * MB);
  unsigned short* encH0  = (unsigned short*)(w + 88 * MB);
  unsigned short* wsDecW = (unsigned short*)(w + 96 * MB);
  unsigned short* wsEncW = (unsigned short*)(w + 112 * MB);
  unsigned short* wsWf   = (unsigned short*)(w + 128 * MB);
  unsigned short* wsWdc  = (unsigned short*)(w + 136 * MB);
  unsigned short* wsWdcT = (unsigned short*)(w + 138 * MB);
  unsigned short* wsWfus = (unsigned short*)(w + 140 * MB);
  unsigned short* wsWec  = (unsigned short*)(w + 148 * MB);
  float*          wsB    = (float*)(w + 149 * MB);
  float*          wsBfus = (float*)(w + 149 * MB + 64 * 1024);
  int*            flag   = (int*)(w + 149 * MB + 96 * 1024);

  const int BIG = 1 << 30;

  detect_kernel<<<1, 256, 0, stream>>>((const unsigned short*)x, flag);

  cvt_plain<<<4096, 256, 0, stream>>>(x,   wsX,  16777216 / 4, flag);
  cvt_plain<<<2048, 256, 0, stream>>>(Wf,  wsWf,  4194304 / 4, flag);
  cvt_plain<<<1024, 256, 0, stream>>>(Wdc, wsWdc, 1048576 / 4, flag);
  cvt_plain<<<22,   256, 0, stream>>>(Wec, wsWec,   22528 / 4, flag);
  cvt_lstmw<<<8192, 256, 0, stream>>>(dWih, dWhh, wsDecW, flag);
  cvt_lstmw<<<8192, 256, 0, stream>>>(eWih, eWhh, wsEncW, flag);
  cvt_bias<<<41, 256, 0, stream>>>(bf_, dbih, dbhh, ebih, ebhh, bdc, bec, wsB, flag);
  trans_wdc<<<dim3(32, 32), 256, 0, stream>>>(Wdc, wsWdcT, flag);
  bias_dot<<<4096, 256, 0, stream>>>(dWih, wsB, wsBfus, flag);

  // Wfus = permWih @ Wdc + permWhh  (rows stay gate-permuted)
  gemm_fused<<<dim3(8, 32), 256, 0, stream>>>(
      wsDecW, 2048, nullptr, 0, BIG, wsWdcT, 1024, 1024, 1024,
      nullptr, EPI_LIN, 0, 0, wsWfus, 1024, wsDecW + 1024, 2048,
      nullptr, flag, nullptr, nullptr, 1024);

  // L1: feats = relu(x @ Wf^T + bf)
  gemm_fused<<<dim3(8, 32), 256, 0, stream>>>(
      wsX, 4096, nullptr, 0, BIG, wsWf, 4096, 4096, 1024,
      wsB, EPI_LIN, 1, 0, feats, 1024, nullptr, 0,
      nullptr, flag, nullptr, nullptr, 1024);

  // decoder step 0: gates = feats @ Wih^T + (bih+bhh); h0=c0=0
  gemm_fused<<<dim3(32, 32), 256, 0, stream>>>(
      feats, 1024, nullptr, 0, BIG, wsDecW, 2048, 1024, 4096,
      wsB + 1024, EPI_LSTM, 0, 1, wsH, 1024, nullptr, 0,
      nullptr, flag, nullptr, cbuf, 1024);

  // decoder steps 1..7: gates = h(d-1) @ Wfus^T + bfus
  for (int d = 1; d < 8; ++d) {
    gemm_fused<<<dim3(32, 32), 256, 0, stream>>>(
        wsH + (size_t)(d - 1) * 4194304, 1024, nullptr, 0, BIG, wsWfus, 1024, 1024, 4096,
        wsBfus, EPI_LSTM, 0, 0, wsH + (size_t)d * 4194304, 1024, nullptr, 0,
        nullptr, flag, nullptr, cbuf, 1024);
  }

  // dec_scores (all 8 steps) = H[32768][1024] @ Wdc^T + bdc; tail rows also
  // write enc_h0 = out(7)/8
  gemm_fused<<<dim3(8, 256), 256, 0, stream>>>(
      wsH, 1024, nullptr, 0, BIG, wsWdc, 1024, 1024, 1024,
      wsB + 9216, EPI_SCORES, 0, 0, nullptr, 0, nullptr, 0,
      d_out, flag, encH0, nullptr, 1024);

  // encoder: one LSTM step on [feats | enc_h0], c0=0; h -> ench
  gemm_fused<<<dim3(32, 32), 256, 0, stream>>>(
      feats, 1024, encH0, 1024, 1024, wsEncW, 2048, 2048, 4096,
      wsB + 5120, EPI_LSTM, 0, 1, ench, 1024, nullptr, 0,
      nullptr, flag, nullptr, cbuf, 1024);

  // classifier: enc_scores = ench @ Wec^T + bec (N=22)
  gemm_fused<<<dim3(1, 32), 256, 0, stream>>>(
      ench, 1024, nullptr, 0, BIG, wsWec, 1024, 1024, 22,
      wsB + 10240, EPI_CLS, 0, 0, nullptr, 0, nullptr, 0,
      d_out, flag, nullptr, nullptr, 22);
}